// Round 9
// baseline (38.807 us; speedup 1.0000x reference)
//
#include <hip/hip_runtime.h>

typedef float f4 __attribute__((ext_vector_type(4)));
typedef float f2 __attribute__((ext_vector_type(2)));
typedef float f32x4 __attribute__((ext_vector_type(4)));
typedef __bf16 bf16x8 __attribute__((ext_vector_type(8)));
typedef __bf16 bf16x4 __attribute__((ext_vector_type(4)));
typedef __bf16 bf16x2 __attribute__((ext_vector_type(2)));

#define NPSIDE 24

// Block = (b, head, 2x4 patch group), 512 threads = 8 waves.
// Staging transforms x -> K/Q/V bf16 ONCE per region into MFMA-ready layouts:
//   Kreg[region_px 240][ch 32 +pad8]  : QK^T B-operand, b128 per-lane reads
//   Qreg[own_px 128][ch 32 +pad8]     : QK^T A-operand
//   Vreg[ch 32][12 rows x 24 +pad4]   : PV B-operand (8 contiguous px/lane)
// Wave wv -> patch (ni0 + (wv>>2), nj0 + (wv&3)); math is pure b128 + MFMA.
__global__ __launch_bounds__(512, 2) void patch_attn(
    const float* __restrict__ x,
    const float* __restrict__ qkv_w,
    const float* __restrict__ qkv_b,
    const float* __restrict__ pos_table,
    const float* __restrict__ wmat,
    __bf16* __restrict__ mid,
    __bf16* __restrict__ wbf)
{
    __shared__ __bf16 Kreg[240][40];    // 19.2 KB
    __shared__ __bf16 Qreg[128][40];    // 10.2 KB
    __shared__ __bf16 Vreg[32][292];    // 18.7 KB
    __shared__ __bf16 Ps[8][16][72];    // 18.4 KB   total 66.5 KB

    const int t = threadIdx.x;

    // side job: out_w fp32 -> bf16 fragment-linear (blocks 0..31, raw id)
    if (blockIdx.x < 32) {
        const int i = (blockIdx.x * 512 + t) * 4;   // o*256+c
        const int o = i >> 8, c = i & 255;
        const f4 v = *(const f4*)&wmat[i];
        bf16x4 ov;
        #pragma unroll
        for (int j = 0; j < 4; ++j) ov[j] = (__bf16)v[j];
        *(bf16x4*)&wbf[((o >> 4) * 8 + (c >> 5)) * 512 + (o & 15) * 32 + (c & 31)] = ov;
    }

    int raw = blockIdx.x;
    const int sw = (raw & 7) * 144 + (raw >> 3);    // XCD swizzle, 1152 = 8*144
    const int pgrp = sw % 72;
    const int bh   = sw / 72;
    const int head = bh & 7;
    const int b    = bh >> 3;
    const int ni0  = (pgrp / 6) * 2;
    const int nj0  = (pgrp % 6) * 4;
    const int c0   = head * 32;
    const float qscale = 0.17677669529663687f;

    // ---- stage + transform: thread = (pixel pair, 8-ch group) ----
    if (t < 480) {
        const int pxp = t % 120;          // pixel pair 0..119
        const int chg = t / 120;          // ch group 0..3
        const int px0 = 2 * pxp;
        const int row = px0 / 20, col = px0 % 20;    // col is even
        const int rg  = min(4 * ni0 + row, 95);
        const int cg  = 4 * nj0 + col;
        const bool own = (row < 8) && (col < 16);
        const float* xb = x + ((size_t)(b * 256 + c0 + 8 * chg) * 96 + rg) * 96;

        bf16x8 kv0, kv1, qv0, qv1;
        #pragma unroll
        for (int j = 0; j < 8; ++j) {
            const int c = c0 + 8 * chg + j;
            const float kw = qkv_w[256 + c], kb = qkv_b[256 + c];
            const float vw = qkv_w[512 + c], vb = qkv_b[512 + c];
            const float qw = qkv_w[c] * qscale, qb = qkv_b[c] * qscale;
            f2 xv;
            if (cg <= 94) {
                xv = *(const f2*)&xb[(size_t)j * 9216 + cg];
            } else {                      // cols 96..99 clamp to col 95
                const float s = xb[(size_t)j * 9216 + 95];
                xv.x = s; xv.y = s;
            }
            kv0[j] = (__bf16)(xv.x * kw + kb);
            kv1[j] = (__bf16)(xv.y * kw + kb);
            bf16x2 vv;
            vv[0] = (__bf16)(xv.x * vw + vb);
            vv[1] = (__bf16)(xv.y * vw + vb);
            *(bf16x2*)&Vreg[8 * chg + j][row * 24 + col] = vv;
            qv0[j] = (__bf16)(xv.x * qw + qb);
            qv1[j] = (__bf16)(xv.y * qw + qb);
        }
        *(bf16x8*)&Kreg[px0][8 * chg]     = kv0;
        *(bf16x8*)&Kreg[px0 + 1][8 * chg] = kv1;
        if (own) {
            const int qpx = row * 16 + col;
            *(bf16x8*)&Qreg[qpx][8 * chg]     = qv0;
            *(bf16x8*)&Qreg[qpx + 1][8 * chg] = qv1;
        }
    }
    __syncthreads();

    const int wv = t >> 6, l = t & 63;
    const int l16 = l & 15, lg = l >> 4;
    const int wni = wv >> 2, wnj = wv & 3;
    const int ni = ni0 + wni, nj = nj0 + wnj;
    const int rb = 4 * wni, cbl = 4 * wnj;   // patch origin within region

    // ---- QK^T: S(16x64) via 4 x mfma_16x16x32, all-b128 operands ----
    const f32x4 zf = {0.f, 0.f, 0.f, 0.f};
    const bf16x8 qf =
        *(const bf16x8*)&Qreg[(rb + (l16 >> 2)) * 16 + cbl + (l16 & 3)][lg * 8];
    f32x4 sacc[4];
    #pragma unroll
    for (int t4 = 0; t4 < 4; ++t4) {
        const int ppx = l16 + 16 * t4;
        const int rpx = (rb + (ppx >> 3)) * 20 + cbl + (ppx & 7);
        const bf16x8 kf = *(const bf16x8*)&Kreg[rpx][lg * 8];
        sacc[t4] = __builtin_amdgcn_mfma_f32_16x16x32_bf16(qf, kf, zf, 0, 0, 0);
    }

    // ---- bias + row softmax ----
    float sv[4][4], rinv[4];
    #pragma unroll
    for (int r = 0; r < 4; ++r) {
        const int qrow = lg * 4 + r;
        const int qi = qrow >> 2, qj = qrow & 3;
        float m = -1e30f;
        #pragma unroll
        for (int t4 = 0; t4 < 4; ++t4) {
            const int kcol = l16 + 16 * t4;
            const int ki = kcol >> 3, kj = kcol & 7;
            const float s = sacc[t4][r]
                + pos_table[((qi - ki + 7) * 15 + (qj - kj + 7)) * 8 + head];
            sv[t4][r] = s;
            m = fmaxf(m, s);
        }
        #pragma unroll
        for (int off = 8; off >= 1; off >>= 1)
            m = fmaxf(m, __shfl_xor(m, off, 16));
        float sum = 0.f;
        #pragma unroll
        for (int t4 = 0; t4 < 4; ++t4) {
            const float p = __expf(sv[t4][r] - m);
            sv[t4][r] = p;
            sum += p;
        }
        #pragma unroll
        for (int off = 8; off >= 1; off >>= 1)
            sum += __shfl_xor(sum, off, 16);
        rinv[r] = 1.0f / sum;
        #pragma unroll
        for (int t4 = 0; t4 < 4; ++t4)
            Ps[wv][qrow][l16 + 16 * t4] = (__bf16)sv[t4][r];
    }
    // Ps is wave-private: compiler's lgkmcnt ordering suffices, no barrier.

    // ---- PV: O(16x32) = P(16x64) * V(64x32) ----
    f32x4 oa = zf, ob = zf;
    #pragma unroll
    for (int kt = 0; kt < 2; ++kt) {
        const bf16x8 pf = *(const bf16x8*)&Ps[wv][l16][lg * 8 + 32 * kt];
        const int voff = (rb + 4 * kt + lg) * 24 + cbl;
        const bf16x8 v0 = *(const bf16x8*)&Vreg[l16][voff];
        const bf16x8 v1 = *(const bf16x8*)&Vreg[16 + l16][voff];
        oa = __builtin_amdgcn_mfma_f32_16x16x32_bf16(pf, v0, oa, 0, 0, 0);
        ob = __builtin_amdgcn_mfma_f32_16x16x32_bf16(pf, v1, ob, 0, 0, 0);
    }

    // ---- epilogue: store O to fragment-linear mid ----
    const int pbase = ni * 384 + lg * 96 + nj * 4;
    __bf16* mbb = mid + (size_t)b * 9216 * 256;
    #pragma unroll
    for (int r = 0; r < 4; ++r) {
        const int p = pbase + r;
        __bf16* dst = mbb + ((p >> 4) * 8 + head) * 512 + (p & 15) * 32;
        dst[l16]      = (__bf16)(oa[r] * rinv[r]);
        dst[16 + l16] = (__bf16)(ob[r] * rinv[r]);
    }
}

// y[b,o,p] = sum_c w[o,c]*mid[b,p,c]; fragment-linear operands.
// Block = 4 ptiles x 2 otiles; 16 KB w-pair staged in LDS once.
__global__ __launch_bounds__(256) void proj(
    const __bf16* __restrict__ wbf,   // fragment-linear [16][8][512]
    const __bf16* __restrict__ mid,   // fragment-linear per b [576][8][512]
    float* __restrict__ y)
{
    __shared__ __align__(16) __bf16 wlds[2][8][512];   // 16 KB

    const int t  = threadIdx.x;
    const int wv = t >> 6;
    const int l  = t & 63;
    const int l16 = l & 15, lg = l >> 4;
    const int fragoff = l16 * 32 + lg * 8;

    int raw = blockIdx.x;                     // 0..1151
    const int sw  = (raw & 7) * 144 + (raw >> 3);
    const int ptg = sw >> 3;                  // 0..143
    const int og2 = sw & 7;                   // 0..7
    const int pt  = ptg * 4 + wv;             // 0..575
    const int ot0 = og2 * 2;
    const int b   = blockIdx.z;

    // stage w pair (fully coalesced: 4 KB per instruction)
    {
        const bf16x8* wsrc = (const bf16x8*)&wbf[(size_t)ot0 * 8 * 512];
        bf16x8* wdst = (bf16x8*)&wlds[0][0][0];
        #pragma unroll
        for (int i = 0; i < 4; ++i)
            wdst[t + 256 * i] = wsrc[t + 256 * i];
    }
    __syncthreads();

    const __bf16* midb = mid + (size_t)b * 9216 * 256;

    f32x4 acc0 = {0.f, 0.f, 0.f, 0.f}, acc1 = {0.f, 0.f, 0.f, 0.f};

    #pragma unroll
    for (int kt = 0; kt < 8; ++kt) {
        const bf16x8 bfr =
            *(const bf16x8*)&midb[(size_t)(pt * 8 + kt) * 512 + fragoff];
        const bf16x8 af0 = *(const bf16x8*)&wlds[0][kt][fragoff];
        const bf16x8 af1 = *(const bf16x8*)&wlds[1][kt][fragoff];
        acc0 = __builtin_amdgcn_mfma_f32_16x16x32_bf16(af0, bfr, acc0, 0, 0, 0);
        acc1 = __builtin_amdgcn_mfma_f32_16x16x32_bf16(af1, bfr, acc1, 0, 0, 0);
    }

    const int p = pt * 16 + l16;
    #pragma unroll
    for (int ot = 0; ot < 2; ++ot) {
        const f32x4 a = ot ? acc1 : acc0;
        const int o = (ot0 + ot) * 16 + lg * 4;
        float* yb = y + ((size_t)b * 256 + o) * 9216 + p;
        #pragma unroll
        for (int r = 0; r < 4; ++r)
            yb[(size_t)r * 9216] = a[r];
    }
}

extern "C" void kernel_launch(void* const* d_in, const int* in_sizes, int n_in,
                              void* d_out, int out_size, void* d_ws, size_t ws_size,
                              hipStream_t stream) {
    const float* x         = (const float*)d_in[0];
    const float* qkv_w     = (const float*)d_in[1];
    const float* qkv_b     = (const float*)d_in[2];
    const float* out_w     = (const float*)d_in[3];
    const float* pos_table = (const float*)d_in[4];
    float* y    = (float*)d_out;
    __bf16* mid = (__bf16*)d_ws;                              // 9.4 MB
    __bf16* wbf = (__bf16*)((char*)d_ws + (12u << 20));       // 128 KB @ 12MB

    patch_attn<<<dim3(1152), dim3(512), 0, stream>>>(
        x, qkv_w, qkv_b, pos_table, out_w, mid, wbf);
    proj<<<dim3(1152, 1, 2), dim3(256), 0, stream>>>(
        wbf, mid, y);
}